// Round 1
// baseline (32.294 us; speedup 1.0000x reference)
//
#include <hip/hip_runtime.h>

// NormalizedBoxCenterEncoder
// B=32, N=100000, M=500
// inputs (float32 per harness threshold analysis):
//   d_in[0] samples (B,N)  float
//   d_in[1] matches (B,N)  int32
//   d_in[2] anchors (B,N,4) float
//   d_in[3] refs    (B,M,4) float
// output d_out float*: targets (B,N,4) then masks (B,N,4) flat-concatenated.

#define BB 32
#define NN 100000
#define MM 500

__global__ __launch_bounds__(256) void nbce_kernel(
    const float*  __restrict__ samples,
    const int*    __restrict__ matches,
    const float4* __restrict__ anchors,
    const float4* __restrict__ refs,
    float4*       __restrict__ targets,
    float4*       __restrict__ masks,
    int total)
{
    int i = blockIdx.x * blockDim.x + threadIdx.x;
    if (i >= total) return;

    int b = i / NN;                 // magic-mul division, cheap
    int idx = matches[i];
    idx = idx < 0 ? 0 : idx;        // jnp.clip(matches, 0)

    float4 rb = refs[b * MM + idx]; // 256 KB table -> L2-resident
    float4 ab = anchors[i];

    float aw = ab.z - ab.x;
    float ah = ab.w - ab.y;
    float ax = ab.x + aw * 0.5f;
    float ay = ab.y + ah * 0.5f;

    float gw = rb.z - rb.x;
    float gh = rb.w - rb.y;
    float gx = rb.x + gw * 0.5f;
    float gy = rb.y + gh * 0.5f;

    // MEANS all 0; STDS = (0.1, 0.1, 0.2, 0.2) -> multiply by 10, 10, 5, 5
    float t0 = ((gx - ax) / aw) * 10.0f;
    float t1 = ((gy - ay) / ah) * 10.0f;
    float t2 = __logf(gw / aw) * 5.0f;
    float t3 = __logf(gh / ah) * 5.0f;

    bool pos = samples[i] > 0.5f;   // samples are +-1
    float m = pos ? 1.0f : 0.0f;

    targets[i] = make_float4(pos ? t0 : 0.0f,
                             pos ? t1 : 0.0f,
                             pos ? t2 : 0.0f,
                             pos ? t3 : 0.0f);
    masks[i] = make_float4(m, m, m, m);
}

extern "C" void kernel_launch(void* const* d_in, const int* in_sizes, int n_in,
                              void* d_out, int out_size, void* d_ws, size_t ws_size,
                              hipStream_t stream)
{
    const float*  samples = (const float*)d_in[0];
    const int*    matches = (const int*)d_in[1];
    const float4* anchors = (const float4*)d_in[2];
    const float4* refs    = (const float4*)d_in[3];

    float* out = (float*)d_out;
    float4* targets = (float4*)out;                       // B*N*4 floats
    float4* masks   = (float4*)(out + (size_t)BB * NN * 4); // next B*N*4 floats

    int total = BB * NN;  // 3,200,000 threads, one per (b,n)
    int block = 256;
    int grid = (total + block - 1) / block;  // 12500 blocks

    nbce_kernel<<<grid, block, 0, stream>>>(samples, matches, anchors, refs,
                                            targets, masks, total);
}